// Round 13
// baseline (161.537 us; speedup 1.0000x reference)
//
#include <hip/hip_runtime.h>
#include <hip/hip_bf16.h>
#include <math.h>

#define Bb 2
#define Lq 384
#define Sk 384
#define Dd 512
#define Hh 256

#define LIST_CAP 65536
#define NROWS (2 * Bb * Lq)          // 1536 total rows (q then k)

// workspace layout (bytes) — f64 regions first for 8B alignment
#define HQD_OFF  0                                   // B*L*H doubles
#define HKD_OFF  (HQD_OFF + Bb*Lq*Hh*8)              // B*S*H doubles
#define PART_OFF (HKD_OFF + Bb*Sk*Hh*8)              // 1536*4*256 doubles
#define GQD_OFF  (PART_OFF + NROWS*4*Hh*8)
#define GKD_OFF  (GQD_OFF + Bb*Hh*8)
#define HQ_OFF   (GKD_OFF + Bb*Hh*8)                 // B*L*H floats
#define HK_OFF   (HQ_OFF + Bb*Lq*Hh*4)               // B*S*H floats
#define SCAL_OFF (HK_OFF + Bb*Sk*Hh*4)               // 2 floats
#define CNT_OFF  (SCAL_OFF + 64)                     // 1 int
#define LIST_OFF (CNT_OFF + 64)                      // LIST_CAP ints

// ---------------------------------------------------------------------------
// fused proj: bx<17 = "smalls" prologue blocks (f64 global-vector dots,
// scal={gwsum,bconst}, cnt=0); bx>=17 = projd_part (f64 row-projection
// partials: 4 rows x 128-d slice x 256 h-threads, grid 1536).
__global__ __launch_bounds__(256) void proj_fused_kernel(
    const float* __restrict__ q, const float* __restrict__ k,
    const float* __restrict__ qg, const float* __restrict__ kg,
    const float* __restrict__ W1,
    const float* __restrict__ gam, const float* __restrict__ bet,
    const float* __restrict__ W2, const float* __restrict__ b2,
    double* __restrict__ gq_d, double* __restrict__ gk_d,
    float* __restrict__ scal, int* __restrict__ cnt,
    double* __restrict__ part)
{
    __shared__ double red[64][5];
    __shared__ float2 red2[256];
    __shared__ __align__(16) float tile[4][128];
    int bx  = blockIdx.x;
    int tid = threadIdx.x;
    if (bx < 16) {
        int isK = bx & 1;
        int b   = (bx >> 1) & 1;
        int hc  = bx >> 2;                  // 0..3
        int hl  = tid >> 2;                 // 0..63
        int dp  = tid & 3;                  // 0..3
        int h   = hc * 64 + hl;
        const float* gv = (isK ? kg : qg) + b * Dd;
        const float* wp = W1 + (isK ? 3 : 2) * Dd * Hh + h;
        int d0 = dp * 128;
        double a0 = 0, a1 = 0, a2 = 0, a3 = 0;
        for (int i = 0; i < 128; i += 4) {
            int d = d0 + i;
            a0 = fma((double)gv[d + 0], (double)wp[(d + 0) * Hh], a0);
            a1 = fma((double)gv[d + 1], (double)wp[(d + 1) * Hh], a1);
            a2 = fma((double)gv[d + 2], (double)wp[(d + 2) * Hh], a2);
            a3 = fma((double)gv[d + 3], (double)wp[(d + 3) * Hh], a3);
        }
        red[hl][dp] = ((a0 + a1) + (a2 + a3));
        __syncthreads();
        if (dp == 0) {
            double s = (red[hl][0] + red[hl][1]) + (red[hl][2] + red[hl][3]);
            (isK ? gk_d : gq_d)[b * Hh + h] = s;
        }
    } else if (bx == 16) {
        if (tid == 0) *cnt = 0;
        float w2v = W2[tid];
        red2[tid] = make_float2(gam[tid] * w2v, bet[tid] * w2v);
        __syncthreads();
        for (int o = 128; o > 0; o >>= 1) {
            if (tid < o) {
                red2[tid].x += red2[tid + o].x;
                red2[tid].y += red2[tid + o].y;
            }
            __syncthreads();
        }
        if (tid == 0) {
            scal[0] = red2[0].x;
            scal[1] = red2[0].y + b2[0];
        }
    } else {
        int bxp = bx - 17;                            // 0..1535
        int ds  = bxp & 3;                            // d-slice 0..3
        int rgid = bxp >> 2;                          // 0..383
        bool isQ = rgid < 192;
        int bb = isQ ? rgid : rgid - 192;
        int b  = bb / 96;
        int rg = bb % 96;                             // 4-row group
        const float* src = isQ ? q : k;
        int woff = isQ ? 0 : Dd * Hh;
        int rowbase = b * Lq + rg * 4;

        if (tid < 128) {
            int row = tid >> 5;
            int c4  = (tid & 31) << 2;
            *reinterpret_cast<float4*>(&tile[row][c4]) =
                *reinterpret_cast<const float4*>(
                    src + (size_t)(rowbase + row) * Dd + ds * 128 + c4);
        }
        __syncthreads();

        const float* wp = W1 + woff + (ds * 128) * Hh + tid;
        double a0 = 0.0, a1 = 0.0, a2 = 0.0, a3 = 0.0;
#pragma unroll 2
        for (int d4 = 0; d4 < 128; d4 += 4) {
            double w0 = (double)wp[(d4 + 0) * Hh];
            double w1 = (double)wp[(d4 + 1) * Hh];
            double w2 = (double)wp[(d4 + 2) * Hh];
            double w3 = (double)wp[(d4 + 3) * Hh];
            float4 t0 = *reinterpret_cast<const float4*>(&tile[0][d4]);
            float4 t1 = *reinterpret_cast<const float4*>(&tile[1][d4]);
            float4 t2 = *reinterpret_cast<const float4*>(&tile[2][d4]);
            float4 t3 = *reinterpret_cast<const float4*>(&tile[3][d4]);
            a0 = fma((double)t0.x, w0, a0); a0 = fma((double)t0.y, w1, a0);
            a0 = fma((double)t0.z, w2, a0); a0 = fma((double)t0.w, w3, a0);
            a1 = fma((double)t1.x, w0, a1); a1 = fma((double)t1.y, w1, a1);
            a1 = fma((double)t1.z, w2, a1); a1 = fma((double)t1.w, w3, a1);
            a2 = fma((double)t2.x, w0, a2); a2 = fma((double)t2.y, w1, a2);
            a2 = fma((double)t2.z, w2, a2); a2 = fma((double)t2.w, w3, a2);
            a3 = fma((double)t3.x, w0, a3); a3 = fma((double)t3.y, w1, a3);
            a3 = fma((double)t3.z, w2, a3); a3 = fma((double)t3.w, w3, a3);
        }
        int rowglob = (isQ ? 0 : Bb * Lq) + rowbase;
        size_t obase = ((size_t)rowglob * 4 + ds) * Hh + tid;
        part[obase]           = a0;
        part[obase + 4 * Hh]  = a1;
        part[obase + 8 * Hh]  = a2;
        part[obase + 12 * Hh] = a3;
    }
}

// ---------------------------------------------------------------------------
// finalize: sum the 4 d-slice partials (deterministic), add global dot;
// emit f64 hq_d/hk_d (cleanup) and f32 hq/hk (+b1 on q) for main.
__global__ __launch_bounds__(256) void finalize_kernel(
    const double* __restrict__ part,
    const double* __restrict__ gq_d, const double* __restrict__ gk_d,
    const float* __restrict__ b1,
    double* __restrict__ hq_d, double* __restrict__ hk_d,
    float* __restrict__ hq, float* __restrict__ hk)
{
    int tid = threadIdx.x;
    int bx  = blockIdx.x;
#pragma unroll
    for (int r = 0; r < 2; ++r) {
        int rowglob = bx * 2 + r;                     // 0..1535
        bool isQ = rowglob < Bb * Lq;
        int rr = isQ ? rowglob : rowglob - Bb * Lq;
        int b  = rr / Lq;
        size_t pbase = ((size_t)rowglob * 4) * Hh + tid;
        double p0 = part[pbase];
        double p1 = part[pbase + 1 * Hh];
        double p2 = part[pbase + 2 * Hh];
        double p3 = part[pbase + 3 * Hh];
        double gl = (isQ ? gq_d : gk_d)[b * Hh + tid];
        double tot = ((p0 + p1) + (p2 + p3)) + gl;
        size_t o = (size_t)rr * Hh + tid;
        if (isQ) {
            hq_d[o] = tot;
            hq[o]   = (float)(tot + (double)b1[tid]);
        } else {
            hk_d[o] = tot;
            hk[o]   = (float)tot;
        }
    }
}

// ---------------------------------------------------------------------------
// tanh-gelu pair accumulate: y2 = 2*gelu_tanh(x) = 2x*sigmoid(x*(K1+K2*x^2)).
__device__ __forceinline__ void gelu2t(float2 hqv, float2 hkv, float2 gwv,
                                       float2& s1, float2& s2, float2& sw)
{
    const float K1 = -2.30220815f;    // -2*log2(e)*sqrt(2/pi)
    const float K2 = -0.10294325f;    // K1 * 0.044715
    float xa = hqv.x + hkv.x,  xb = hqv.y + hkv.y;
    float x2a = xa * xa,       x2b = xb * xb;
    float pa = fmaf(K2, x2a, K1), pb = fmaf(K2, x2b, K1);
    float za = xa * pa,        zb = xb * pb;
    float ea = __builtin_amdgcn_exp2f(za);
    float eb = __builtin_amdgcn_exp2f(zb);
    float ra = __builtin_amdgcn_rcpf(1.0f + ea);
    float rb = __builtin_amdgcn_rcpf(1.0f + eb);
    float ya = (xa + xa) * ra, yb = (xb + xb) * rb;  // = 2*gelu
    s1.x += ya;                s1.y += yb;
    s2.x = fmaf(ya, ya, s2.x); s2.y = fmaf(yb, yb, s2.y);
    sw.x = fmaf(ya, gwv.x, sw.x); sw.y = fmaf(yb, gwv.y, sw.y);
}

// ---------------------------------------------------------------------------
// main: 32x16 (l,s) tile per 512-thread block. Phase A computes the sim
// dot-products in-block (q/k chunks staged in LDS, lane pair splits the d
// range, __shfl_xor combine) — the separate sim kernel + partial planes are
// gone. Phase B (same LDS, union-aliased) runs the gelu/LN/threshold pass.
__global__ __launch_bounds__(512) void main_kernel(
    const float* __restrict__ q, const float* __restrict__ k,
    const float* __restrict__ hq, const float* __restrict__ hk,
    const float* __restrict__ gam, const float* __restrict__ W2,
    const float* __restrict__ scal,
    const float* __restrict__ gu, float* __restrict__ out,
    int* __restrict__ cnt, int* __restrict__ list)
{
    // union: phase A uses qs[32][132]+ks[16][132] (24.8 KB);
    //        phase B uses hq_t[32][260]+hk_t[16][260]+gw_s[256] (50.9 KB)
    __shared__ __align__(16) float smem[32 * 260 + 16 * 260 + 256];
    float (*qs)[132]   = (float (*)[132])smem;
    float (*ks)[132]   = (float (*)[132])(smem + 32 * 132);
    float (*hq_t)[260] = (float (*)[260])smem;
    float (*hk_t)[260] = (float (*)[260])(smem + 32 * 260);
    float* gw_s        = smem + 32 * 260 + 16 * 260;

    int tid = threadIdx.x;
    int bx = blockIdx.x;
    int b  = bx / (12 * 24);
    int r  = bx % (12 * 24);
    int lt = r / 24, st = r % 24;          // l-tile 32 rows, s-tile 16 cols

    int opair = tid >> 1;                  // 0..255: output-pair id
    int hh    = tid & 1;                   // d-/h-half
    int tl = opair >> 4, ts = opair & 15;

    // ---------------- phase A: sim for this tile ----------------
    const float* qb = q + (size_t)(b * Lq + lt * 32) * Dd;
    const float* kb = k + (size_t)(b * Sk + st * 16) * Dd;
    float sva = 0.f, svb = 0.f;
    for (int c = 0; c < Dd; c += 128) {
        __syncthreads();                   // prior chunk reads complete
        for (int i = tid; i < 1536; i += 512) {   // 1024 q-f4 + 512 k-f4
            if (i < 1024) {
                int row = i >> 5, c4 = (i & 31) << 2;
                *reinterpret_cast<float4*>(&qs[row][c4]) =
                    *reinterpret_cast<const float4*>(qb + (size_t)row * Dd + c + c4);
            } else {
                int j = i - 1024;
                int row = j >> 5, c4 = (j & 31) << 2;
                *reinterpret_cast<float4*>(&ks[row][c4]) =
                    *reinterpret_cast<const float4*>(kb + (size_t)row * Dd + c + c4);
            }
        }
        __syncthreads();
        int d0 = hh << 6;                  // lane takes 64 of the 128 d's
#pragma unroll 4
        for (int d4 = d0; d4 < d0 + 64; d4 += 4) {
            float4 qa = *reinterpret_cast<const float4*>(&qs[tl][d4]);
            float4 qc = *reinterpret_cast<const float4*>(&qs[tl + 16][d4]);
            float4 kk = *reinterpret_cast<const float4*>(&ks[ts][d4]);
            sva = fmaf(qa.x, kk.x, sva); sva = fmaf(qa.y, kk.y, sva);
            sva = fmaf(qa.z, kk.z, sva); sva = fmaf(qa.w, kk.w, sva);
            svb = fmaf(qc.x, kk.x, svb); svb = fmaf(qc.y, kk.y, svb);
            svb = fmaf(qc.z, kk.z, svb); svb = fmaf(qc.w, kk.w, svb);
        }
    }
    sva += __shfl_xor(sva, 1, 64);
    svb += __shfl_xor(svb, 1, 64);
    const float sc = 0.04419417382415922f;   // 1/sqrt(512)
    sva *= sc; svb *= sc;

    // ---------------- phase B: gelu/LN/threshold ----------------
    __syncthreads();                       // phase-A reads complete
    const float* hqb = hq + (b * Lq + lt * 32) * Hh;
    const float* hkb = hk + (b * Sk + st * 16) * Hh;
#pragma unroll
    for (int i = 0; i < 4; ++i) {          // 32 rows x 64 float4 = 2048
        int idx4 = i * 512 + tid;
        int row  = idx4 >> 6;
        int col4 = (idx4 & 63) << 2;
        *reinterpret_cast<float4*>(&hq_t[row][col4]) =
            *reinterpret_cast<const float4*>(hqb + row * Hh + col4);
    }
#pragma unroll
    for (int i = 0; i < 2; ++i) {          // 16 rows x 64 float4 = 1024
        int idx4 = i * 512 + tid;
        int row  = idx4 >> 6;
        int col4 = (idx4 & 63) << 2;
        *reinterpret_cast<float4*>(&hk_t[row][col4]) =
            *reinterpret_cast<const float4*>(hkb + row * Hh + col4);
    }
    if (tid < 256) gw_s[tid] = gam[tid] * W2[tid];
    __syncthreads();
    float gwsum  = scal[0];
    float bconst = scal[1];

    float2 s1a = make_float2(0.f, 0.f), s2a = s1a, swa = s1a;
    float2 s1b = s1a, s2b = s1a, swb = s1a;
    int h0 = hh << 7;                      // 0 or 128
#pragma unroll 2
    for (int h4 = h0; h4 < h0 + 128; h4 += 4) {
        float4 ha = *reinterpret_cast<const float4*>(&hq_t[tl][h4]);
        float4 hb = *reinterpret_cast<const float4*>(&hq_t[tl + 16][h4]);
        float4 kk = *reinterpret_cast<const float4*>(&hk_t[ts][h4]);
        float4 g4 = *reinterpret_cast<const float4*>(&gw_s[h4]);
        gelu2t(make_float2(ha.x, ha.y), make_float2(kk.x, kk.y),
               make_float2(g4.x, g4.y), s1a, s2a, swa);
        gelu2t(make_float2(ha.z, ha.w), make_float2(kk.z, kk.w),
               make_float2(g4.z, g4.w), s1a, s2a, swa);
        gelu2t(make_float2(hb.x, hb.y), make_float2(kk.x, kk.y),
               make_float2(g4.x, g4.y), s1b, s2b, swb);
        gelu2t(make_float2(hb.z, hb.w), make_float2(kk.z, kk.w),
               make_float2(g4.z, g4.w), s1b, s2b, swb);
    }
    float S1a = s1a.x + s1a.y;  S1a += __shfl_xor(S1a, 1, 64);
    float S2a = s2a.x + s2a.y;  S2a += __shfl_xor(S2a, 1, 64);
    float SWa = swa.x + swa.y;  SWa += __shfl_xor(SWa, 1, 64);
    float S1b = s1b.x + s1b.y;  S1b += __shfl_xor(S1b, 1, 64);
    float S2b = s2b.x + s2b.y;  S2b += __shfl_xor(S2b, 1, 64);
    float SWb = swb.x + swb.y;  SWb += __shfl_xor(SWb, 1, 64);

    float S1 = hh ? S1b : S1a;
    float S2 = hh ? S2b : S2a;
    float SW = 0.5f * (hh ? SWb : SWa);
    float sv = hh ? svb : sva;
    float mu   = S1 * (1.0f / 512.0f);
    float var  = S2 * (1.0f / 1024.0f) - mu * mu;
    float rstd = rsqrtf(var + 1e-5f);
    float thr  = rstd * (SW - mu * gwsum) + bconst;

    int l = lt * 32 + tl + hh * 16, s = st * 16 + ts;
    int idx = (b * Lq + l) * Sk + s;
    float2 uv = reinterpret_cast<const float2*>(gu)[idx];
    float u0 = fminf(fmaxf(uv.x, 1e-6f), 1.0f - 1e-6f);
    float u1 = fminf(fmaxf(uv.y, 1e-6f), 1.0f - 1e-6f);
    float g0 = -logf(-logf(u0));
    float g1 = -logf(-logf(u1));
    float t  = 0.2f * (sv - thr) + (g1 - g0);
    out[idx] = t > 0.0f ? 1.0f : 0.0f;
    if (fabsf(t) < 2e-3f) {
        int p = atomicAdd(cnt, 1);
        if (p < LIST_CAP) list[p] = idx;
    }
}

// ---------------------------------------------------------------------------
// cleanup: per flagged item, exact-f64 finish using precomputed projections.
__global__ __launch_bounds__(256) void cleanup_kernel(
    const float* __restrict__ q, const float* __restrict__ k,
    const double* __restrict__ hq_d, const double* __restrict__ hk_d,
    const float* __restrict__ b1,
    const float* __restrict__ gam, const float* __restrict__ bet,
    const float* __restrict__ W2, const float* __restrict__ b2,
    const float* __restrict__ gu, float* __restrict__ out,
    const int* __restrict__ cnt, const int* __restrict__ list)
{
    __shared__ double s0[256], s1[256], s2[256], s3[256];
    int tid = threadIdx.x;
    int n = *cnt;
    if (n > LIST_CAP) n = LIST_CAP;
    if (n == 0) return;

    double gw  = (double)gam[tid] * (double)W2[tid];
    double b1d = (double)b1[tid];
    s0[tid] = (double)bet[tid] * (double)W2[tid];
    s1[tid] = gw;
    __syncthreads();
    for (int o = 128; o > 0; o >>= 1) {
        if (tid < o) { s0[tid] += s0[tid + o]; s1[tid] += s1[tid + o]; }
        __syncthreads();
    }
    double bconst = s0[0] + (double)b2[0];
    double gwsum  = s1[0];
    __syncthreads();

    for (int it = blockIdx.x; it < n; it += gridDim.x) {
        int idx = list[it];
        int b   = idx / (Lq * Sk);
        int rem = idx % (Lq * Sk);
        int l = rem / Sk, s = rem % Sk;
        double x = (hq_d[(b * Lq + l) * Hh + tid]
                  + hk_d[(b * Sk + s) * Hh + tid]) + b1d;
        double y = 0.5 * x * (1.0 + erf(x * 0.70710678118654752440));
        const float* qrow = q + (b * Lq + l) * Dd;
        const float* krow = k + (b * Sk + s) * Dd;
        double sp = (double)qrow[tid] * (double)krow[tid]
                  + (double)qrow[tid + 256] * (double)krow[tid + 256];
        s0[tid] = y; s1[tid] = y * y; s2[tid] = y * gw; s3[tid] = sp;
        __syncthreads();
        for (int o = 128; o > 0; o >>= 1) {
            if (tid < o) {
                s0[tid] += s0[tid + o]; s1[tid] += s1[tid + o];
                s2[tid] += s2[tid + o]; s3[tid] += s3[tid + o];
            }
            __syncthreads();
        }
        if (tid == 0) {
            double mu   = s0[0] * (1.0 / 256.0);
            double var  = s1[0] * (1.0 / 256.0) - mu * mu;
            double rstd = 1.0 / sqrt(var + 1e-5);
            double thr  = rstd * (s2[0] - mu * gwsum) + bconst;
            double simv = s3[0] / 22.627416997969522;   // sqrt(512)
            float2 uv = reinterpret_cast<const float2*>(gu)[idx];
            double u0 = fmin(fmax((double)uv.x, 1e-6), 1.0 - 1e-6);
            double u1 = fmin(fmax((double)uv.y, 1e-6), 1.0 - 1e-6);
            double g0 = -log(-log(u0));
            double g1 = -log(-log(u1));
            double t  = 0.2 * (simv - thr) + (g1 - g0);
            out[idx] = t > 0.0 ? 1.0f : 0.0f;
        }
        __syncthreads();
    }
}

// ---------------------------------------------------------------------------
extern "C" void kernel_launch(void* const* d_in, const int* in_sizes, int n_in,
                              void* d_out, int out_size, void* d_ws, size_t ws_size,
                              hipStream_t stream)
{
    const float* q   = (const float*)d_in[0];
    const float* k   = (const float*)d_in[1];
    const float* qg  = (const float*)d_in[2];
    const float* kg  = (const float*)d_in[3];
    const float* W1  = (const float*)d_in[4];
    const float* b1  = (const float*)d_in[5];
    const float* gam = (const float*)d_in[6];
    const float* bet = (const float*)d_in[7];
    const float* W2  = (const float*)d_in[8];
    const float* b2  = (const float*)d_in[9];
    const float* gu  = (const float*)d_in[10];
    float* out = (float*)d_out;

    char*   ws   = (char*)d_ws;
    double* hq_d = (double*)(ws + HQD_OFF);
    double* hk_d = (double*)(ws + HKD_OFF);
    double* part = (double*)(ws + PART_OFF);
    double* gq_d = (double*)(ws + GQD_OFF);
    double* gk_d = (double*)(ws + GKD_OFF);
    float*  hq   = (float*)(ws + HQ_OFF);
    float*  hk   = (float*)(ws + HK_OFF);
    float*  scal = (float*)(ws + SCAL_OFF);
    int*    cnt  = (int*)(ws + CNT_OFF);
    int*    list = (int*)(ws + LIST_OFF);

    proj_fused_kernel<<<17 + NROWS, 256, 0, stream>>>(
        q, k, qg, kg, W1, gam, bet, W2, b2, gq_d, gk_d, scal, cnt, part);
    finalize_kernel<<<NROWS / 2, 256, 0, stream>>>(
        part, gq_d, gk_d, b1, hq_d, hk_d, hq, hk);
    main_kernel<<<Bb * 12 * 24, 512, 0, stream>>>(
        q, k, hq, hk, gam, W2, scal, gu, out, cnt, list);
    cleanup_kernel<<<768, 256, 0, stream>>>(
        q, k, hq_d, hk_d, b1, gam, bet, W2, b2, gu, out, cnt, list);
}

// Round 14
// 156.030 us; speedup vs baseline: 1.0353x; 1.0353x over previous
//
#include <hip/hip_runtime.h>
#include <hip/hip_bf16.h>
#include <math.h>

#define Bb 2
#define Lq 384
#define Sk 384
#define Dd 512
#define Hh 256

#define LIST_CAP 65536
#define NROWS (2 * Bb * Lq)          // 1536 total rows (q then k)
#define PLANE (Bb * Lq * Sk)         // elements per sim partial plane

// workspace layout (bytes) — f64 regions first for 8B alignment
#define HQD_OFF  0                                   // B*L*H doubles
#define HKD_OFF  (HQD_OFF + Bb*Lq*Hh*8)              // B*S*H doubles
#define PART_OFF (HKD_OFF + Bb*Sk*Hh*8)              // 1536*4*256 doubles
#define GQD_OFF  (PART_OFF + NROWS*4*Hh*8)
#define GKD_OFF  (GQD_OFF + Bb*Hh*8)
#define HQ_OFF   (GKD_OFF + Bb*Hh*8)                 // B*L*H floats
#define HK_OFF   (HQ_OFF + Bb*Lq*Hh*4)               // B*S*H floats
#define SIM_OFF  (HK_OFF + Bb*Sk*Hh*4)               // 8 planes x B*L*S floats
#define SCAL_OFF (SIM_OFF + 8*PLANE*4)               // 2 floats
#define CNT_OFF  (SCAL_OFF + 64)                     // 1 int
#define LIST_OFF (CNT_OFF + 64)                      // LIST_CAP ints

// ---------------------------------------------------------------------------
// fused proj: bx<17 = "smalls" prologue blocks (f64 global-vector dots,
// scal={gwsum,bconst}, cnt=0); bx>=17 = projd_part (f64 row-projection
// partials: 4 rows x 128-d slice x 256 h-threads, grid 1536).
__global__ __launch_bounds__(256) void proj_fused_kernel(
    const float* __restrict__ q, const float* __restrict__ k,
    const float* __restrict__ qg, const float* __restrict__ kg,
    const float* __restrict__ W1,
    const float* __restrict__ gam, const float* __restrict__ bet,
    const float* __restrict__ W2, const float* __restrict__ b2,
    double* __restrict__ gq_d, double* __restrict__ gk_d,
    float* __restrict__ scal, int* __restrict__ cnt,
    double* __restrict__ part)
{
    __shared__ double red[64][5];
    __shared__ float2 red2[256];
    __shared__ __align__(16) float tile[4][128];
    int bx  = blockIdx.x;
    int tid = threadIdx.x;
    if (bx < 16) {
        int isK = bx & 1;
        int b   = (bx >> 1) & 1;
        int hc  = bx >> 2;                  // 0..3
        int hl  = tid >> 2;                 // 0..63
        int dp  = tid & 3;                  // 0..3
        int h   = hc * 64 + hl;
        const float* gv = (isK ? kg : qg) + b * Dd;
        const float* wp = W1 + (isK ? 3 : 2) * Dd * Hh + h;
        int d0 = dp * 128;
        double a0 = 0, a1 = 0, a2 = 0, a3 = 0;
        for (int i = 0; i < 128; i += 4) {
            int d = d0 + i;
            a0 = fma((double)gv[d + 0], (double)wp[(d + 0) * Hh], a0);
            a1 = fma((double)gv[d + 1], (double)wp[(d + 1) * Hh], a1);
            a2 = fma((double)gv[d + 2], (double)wp[(d + 2) * Hh], a2);
            a3 = fma((double)gv[d + 3], (double)wp[(d + 3) * Hh], a3);
        }
        red[hl][dp] = ((a0 + a1) + (a2 + a3));
        __syncthreads();
        if (dp == 0) {
            double s = (red[hl][0] + red[hl][1]) + (red[hl][2] + red[hl][3]);
            (isK ? gk_d : gq_d)[b * Hh + h] = s;
        }
    } else if (bx == 16) {
        if (tid == 0) *cnt = 0;
        float w2v = W2[tid];
        red2[tid] = make_float2(gam[tid] * w2v, bet[tid] * w2v);
        __syncthreads();
        for (int o = 128; o > 0; o >>= 1) {
            if (tid < o) {
                red2[tid].x += red2[tid + o].x;
                red2[tid].y += red2[tid + o].y;
            }
            __syncthreads();
        }
        if (tid == 0) {
            scal[0] = red2[0].x;
            scal[1] = red2[0].y + b2[0];
        }
    } else {
        int bxp = bx - 17;                            // 0..1535
        int ds  = bxp & 3;                            // d-slice 0..3
        int rgid = bxp >> 2;                          // 0..383
        bool isQ = rgid < 192;
        int bb = isQ ? rgid : rgid - 192;
        int b  = bb / 96;
        int rg = bb % 96;                             // 4-row group
        const float* src = isQ ? q : k;
        int woff = isQ ? 0 : Dd * Hh;
        int rowbase = b * Lq + rg * 4;

        if (tid < 128) {
            int row = tid >> 5;
            int c4  = (tid & 31) << 2;
            *reinterpret_cast<float4*>(&tile[row][c4]) =
                *reinterpret_cast<const float4*>(
                    src + (size_t)(rowbase + row) * Dd + ds * 128 + c4);
        }
        __syncthreads();

        const float* wp = W1 + woff + (ds * 128) * Hh + tid;
        double a0 = 0.0, a1 = 0.0, a2 = 0.0, a3 = 0.0;
#pragma unroll 2
        for (int d4 = 0; d4 < 128; d4 += 4) {
            double w0 = (double)wp[(d4 + 0) * Hh];
            double w1 = (double)wp[(d4 + 1) * Hh];
            double w2 = (double)wp[(d4 + 2) * Hh];
            double w3 = (double)wp[(d4 + 3) * Hh];
            float4 t0 = *reinterpret_cast<const float4*>(&tile[0][d4]);
            float4 t1 = *reinterpret_cast<const float4*>(&tile[1][d4]);
            float4 t2 = *reinterpret_cast<const float4*>(&tile[2][d4]);
            float4 t3 = *reinterpret_cast<const float4*>(&tile[3][d4]);
            a0 = fma((double)t0.x, w0, a0); a0 = fma((double)t0.y, w1, a0);
            a0 = fma((double)t0.z, w2, a0); a0 = fma((double)t0.w, w3, a0);
            a1 = fma((double)t1.x, w0, a1); a1 = fma((double)t1.y, w1, a1);
            a1 = fma((double)t1.z, w2, a1); a1 = fma((double)t1.w, w3, a1);
            a2 = fma((double)t2.x, w0, a2); a2 = fma((double)t2.y, w1, a2);
            a2 = fma((double)t2.z, w2, a2); a2 = fma((double)t2.w, w3, a2);
            a3 = fma((double)t3.x, w0, a3); a3 = fma((double)t3.y, w1, a3);
            a3 = fma((double)t3.z, w2, a3); a3 = fma((double)t3.w, w3, a3);
        }
        int rowglob = (isQ ? 0 : Bb * Lq) + rowbase;
        size_t obase = ((size_t)rowglob * 4 + ds) * Hh + tid;
        part[obase]           = a0;
        part[obase + 4 * Hh]  = a1;
        part[obase + 8 * Hh]  = a2;
        part[obase + 12 * Hh] = a3;
    }
}

// ---------------------------------------------------------------------------
// finalize: sum the 4 d-slice partials (deterministic), add global dot;
// emit f64 hq_d/hk_d (cleanup) and f32 hq/hk (+b1 on q) for main.
__global__ __launch_bounds__(256) void finalize_kernel(
    const double* __restrict__ part,
    const double* __restrict__ gq_d, const double* __restrict__ gk_d,
    const float* __restrict__ b1,
    double* __restrict__ hq_d, double* __restrict__ hk_d,
    float* __restrict__ hq, float* __restrict__ hk)
{
    int tid = threadIdx.x;
    int bx  = blockIdx.x;
#pragma unroll
    for (int r = 0; r < 2; ++r) {
        int rowglob = bx * 2 + r;                     // 0..1535
        bool isQ = rowglob < Bb * Lq;
        int rr = isQ ? rowglob : rowglob - Bb * Lq;
        int b  = rr / Lq;
        size_t pbase = ((size_t)rowglob * 4) * Hh + tid;
        double p0 = part[pbase];
        double p1 = part[pbase + 1 * Hh];
        double p2 = part[pbase + 2 * Hh];
        double p3 = part[pbase + 3 * Hh];
        double gl = (isQ ? gq_d : gk_d)[b * Hh + tid];
        double tot = ((p0 + p1) + (p2 + p3)) + gl;
        size_t o = (size_t)rr * Hh + tid;
        if (isQ) {
            hq_d[o] = tot;
            hq[o]   = (float)(tot + (double)b1[tid]);
        } else {
            hk_d[o] = tot;
            hk[o]   = (float)tot;
        }
    }
}

// ---------------------------------------------------------------------------
// sim: 64x64 output tile, 4x4 per thread, transposed LDS (d-major), split-K
// x8 partial planes; main sums the planes.
__global__ __launch_bounds__(256) void sim_kernel(
    const float* __restrict__ q, const float* __restrict__ k,
    float* __restrict__ simP)
{
    __shared__ __align__(16) float qs_t[64][68];
    __shared__ __align__(16) float ks_t[64][68];
    int tid = threadIdx.x;
    int bx  = blockIdx.x;              // 0..575
    int kc  = bx / 72;                 // 0..7: 64-d slice
    int r   = bx % 72;
    int b   = r / 36;  r %= 36;
    int lt  = r / 6,  st = r % 6;

    const float* qb = q + (size_t)(b * Lq + lt * 64) * Dd + kc * 64;
    const float* kb = k + (size_t)(b * Sk + st * 64) * Dd + kc * 64;
#pragma unroll
    for (int it = 0; it < 4; ++it) {   // 64 rows x 16 float4 = 1024
        int i   = it * 256 + tid;
        int row = i >> 4;
        int c4  = (i & 15) << 2;
        float4 vq = *reinterpret_cast<const float4*>(qb + (size_t)row * Dd + c4);
        float4 vk = *reinterpret_cast<const float4*>(kb + (size_t)row * Dd + c4);
        qs_t[c4 + 0][row] = vq.x; qs_t[c4 + 1][row] = vq.y;
        qs_t[c4 + 2][row] = vq.z; qs_t[c4 + 3][row] = vq.w;
        ks_t[c4 + 0][row] = vk.x; ks_t[c4 + 1][row] = vk.y;
        ks_t[c4 + 2][row] = vk.z; ks_t[c4 + 3][row] = vk.w;
    }
    __syncthreads();

    int tl = tid >> 4, ts = tid & 15;
    float acc[4][4];
#pragma unroll
    for (int i = 0; i < 4; ++i)
#pragma unroll
        for (int j = 0; j < 4; ++j) acc[i][j] = 0.f;

#pragma unroll 4
    for (int dd = 0; dd < 64; ++dd) {
        float4 qa = *reinterpret_cast<const float4*>(&qs_t[dd][4 * tl]);
        float4 kb4 = *reinterpret_cast<const float4*>(&ks_t[dd][4 * ts]);
        acc[0][0] = fmaf(qa.x, kb4.x, acc[0][0]);
        acc[0][1] = fmaf(qa.x, kb4.y, acc[0][1]);
        acc[0][2] = fmaf(qa.x, kb4.z, acc[0][2]);
        acc[0][3] = fmaf(qa.x, kb4.w, acc[0][3]);
        acc[1][0] = fmaf(qa.y, kb4.x, acc[1][0]);
        acc[1][1] = fmaf(qa.y, kb4.y, acc[1][1]);
        acc[1][2] = fmaf(qa.y, kb4.z, acc[1][2]);
        acc[1][3] = fmaf(qa.y, kb4.w, acc[1][3]);
        acc[2][0] = fmaf(qa.z, kb4.x, acc[2][0]);
        acc[2][1] = fmaf(qa.z, kb4.y, acc[2][1]);
        acc[2][2] = fmaf(qa.z, kb4.z, acc[2][2]);
        acc[2][3] = fmaf(qa.z, kb4.w, acc[2][3]);
        acc[3][0] = fmaf(qa.w, kb4.x, acc[3][0]);
        acc[3][1] = fmaf(qa.w, kb4.y, acc[3][1]);
        acc[3][2] = fmaf(qa.w, kb4.z, acc[3][2]);
        acc[3][3] = fmaf(qa.w, kb4.w, acc[3][3]);
    }

    const float sc = 0.04419417382415922f;   // 1/sqrt(512)
    float* dst = simP + (size_t)kc * PLANE;
    int l0 = lt * 64 + 4 * tl, s0 = st * 64 + 4 * ts;
#pragma unroll
    for (int i = 0; i < 4; ++i) {
        float4 v = make_float4(acc[i][0] * sc, acc[i][1] * sc,
                               acc[i][2] * sc, acc[i][3] * sc);
        *reinterpret_cast<float4*>(&dst[(size_t)(b * Lq + l0 + i) * Sk + s0]) = v;
    }
}

// ---------------------------------------------------------------------------
// tanh-gelu pair accumulate: y2 = 2*gelu_tanh(x) = 2x*sigmoid(x*(K1+K2*x^2)).
__device__ __forceinline__ void gelu2t(float2 hqv, float2 hkv, float2 gwv,
                                       float2& s1, float2& s2, float2& sw)
{
    const float K1 = -2.30220815f;    // -2*log2(e)*sqrt(2/pi)
    const float K2 = -0.10294325f;    // K1 * 0.044715
    float xa = hqv.x + hkv.x,  xb = hqv.y + hkv.y;
    float x2a = xa * xa,       x2b = xb * xb;
    float pa = fmaf(K2, x2a, K1), pb = fmaf(K2, x2b, K1);
    float za = xa * pa,        zb = xb * pb;
    float ea = __builtin_amdgcn_exp2f(za);
    float eb = __builtin_amdgcn_exp2f(zb);
    float ra = __builtin_amdgcn_rcpf(1.0f + ea);
    float rb = __builtin_amdgcn_rcpf(1.0f + eb);
    float ya = (xa + xa) * ra, yb = (xb + xb) * rb;  // = 2*gelu
    s1.x += ya;                s1.y += yb;
    s2.x = fmaf(ya, ya, s2.x); s2.y = fmaf(yb, yb, s2.y);
    sw.x = fmaf(ya, gwv.x, sw.x); sw.y = fmaf(yb, gwv.y, sw.y);
}

// ---------------------------------------------------------------------------
// main: 32x16 (l,s) tile per 512-thread block; lane pair shares a 2-row
// output set. h-split is INTERLEAVED at float4 granularity (h4 = 8j+4*hh):
// lanes hh=0/1 hit adjacent 4-bank windows instead of the SAME window
// (blocked split had 128 ≡ 0 mod 32 banks -> 4-way conflict, 5.9M cycles
// measured in R13). Combine via __shfl_xor(.,1).
__global__ __launch_bounds__(512) void main_kernel(
    const float* __restrict__ hq, const float* __restrict__ hk,
    const float* __restrict__ simP,
    const float* __restrict__ gam, const float* __restrict__ W2,
    const float* __restrict__ scal,
    const float* __restrict__ gu, float* __restrict__ out,
    int* __restrict__ cnt, int* __restrict__ list)
{
    __shared__ __align__(16) float hq_t[32][260];
    __shared__ __align__(16) float hk_t[16][260];
    __shared__ __align__(16) float gw_s[256];
    int tid = threadIdx.x;
    int bx = blockIdx.x;
    int b  = bx / (12 * 24);
    int r  = bx % (12 * 24);
    int lt = r / 24, st = r % 24;          // l-tile 32 rows, s-tile 16 cols

    const float* hqb = hq + (b * Lq + lt * 32) * Hh;
    const float* hkb = hk + (b * Sk + st * 16) * Hh;
#pragma unroll
    for (int i = 0; i < 4; ++i) {          // 32 rows x 64 float4 = 2048
        int idx4 = i * 512 + tid;
        int row  = idx4 >> 6;
        int col4 = (idx4 & 63) << 2;
        *reinterpret_cast<float4*>(&hq_t[row][col4]) =
            *reinterpret_cast<const float4*>(hqb + row * Hh + col4);
    }
#pragma unroll
    for (int i = 0; i < 2; ++i) {          // 16 rows x 64 float4 = 1024
        int idx4 = i * 512 + tid;
        int row  = idx4 >> 6;
        int col4 = (idx4 & 63) << 2;
        *reinterpret_cast<float4*>(&hk_t[row][col4]) =
            *reinterpret_cast<const float4*>(hkb + row * Hh + col4);
    }
    if (tid < 256) gw_s[tid] = gam[tid] * W2[tid];
    __syncthreads();
    float gwsum  = scal[0];
    float bconst = scal[1];

    int opair = tid >> 1;                  // 0..255: output-pair id
    int hh    = tid & 1;                   // h-half (interleaved)
    int tl = opair >> 4, ts = opair & 15;

    float2 s1a = make_float2(0.f, 0.f), s2a = s1a, swa = s1a;
    float2 s1b = s1a, s2b = s1a, swb = s1a;
    int hoff = hh << 2;                    // 0 or 4 (float4 interleave)
#pragma unroll 2
    for (int j = 0; j < 32; ++j) {
        int h4 = 8 * j + hoff;             // lane's float4 group
        float4 ha = *reinterpret_cast<const float4*>(&hq_t[tl][h4]);
        float4 hb = *reinterpret_cast<const float4*>(&hq_t[tl + 16][h4]);
        float4 kk = *reinterpret_cast<const float4*>(&hk_t[ts][h4]);
        float4 g4 = *reinterpret_cast<const float4*>(&gw_s[h4]);
        gelu2t(make_float2(ha.x, ha.y), make_float2(kk.x, kk.y),
               make_float2(g4.x, g4.y), s1a, s2a, swa);
        gelu2t(make_float2(ha.z, ha.w), make_float2(kk.z, kk.w),
               make_float2(g4.z, g4.w), s1a, s2a, swa);
        gelu2t(make_float2(hb.x, hb.y), make_float2(kk.x, kk.y),
               make_float2(g4.x, g4.y), s1b, s2b, swb);
        gelu2t(make_float2(hb.z, hb.w), make_float2(kk.z, kk.w),
               make_float2(g4.z, g4.w), s1b, s2b, swb);
    }
    float S1a = s1a.x + s1a.y;  S1a += __shfl_xor(S1a, 1, 64);
    float S2a = s2a.x + s2a.y;  S2a += __shfl_xor(S2a, 1, 64);
    float SWa = swa.x + swa.y;  SWa += __shfl_xor(SWa, 1, 64);
    float S1b = s1b.x + s1b.y;  S1b += __shfl_xor(S1b, 1, 64);
    float S2b = s2b.x + s2b.y;  S2b += __shfl_xor(S2b, 1, 64);
    float SWb = swb.x + swb.y;  SWb += __shfl_xor(SWb, 1, 64);

    float S1 = hh ? S1b : S1a;
    float S2 = hh ? S2b : S2a;
    float SW = 0.5f * (hh ? SWb : SWa);
    float mu   = S1 * (1.0f / 512.0f);
    float var  = S2 * (1.0f / 1024.0f) - mu * mu;
    float rstd = rsqrtf(var + 1e-5f);
    float thr  = rstd * (SW - mu * gwsum) + bconst;

    int l = lt * 32 + tl + hh * 16, s = st * 16 + ts;
    int idx = (b * Lq + l) * Sk + s;
    float sv = 0.f;
#pragma unroll
    for (int p = 0; p < 8; ++p) sv += simP[(size_t)p * PLANE + idx];
    float2 uv = reinterpret_cast<const float2*>(gu)[idx];
    float u0 = fminf(fmaxf(uv.x, 1e-6f), 1.0f - 1e-6f);
    float u1 = fminf(fmaxf(uv.y, 1e-6f), 1.0f - 1e-6f);
    float g0 = -logf(-logf(u0));
    float g1 = -logf(-logf(u1));
    float t  = 0.2f * (sv - thr) + (g1 - g0);
    out[idx] = t > 0.0f ? 1.0f : 0.0f;
    if (fabsf(t) < 2e-3f) {
        int p = atomicAdd(cnt, 1);
        if (p < LIST_CAP) list[p] = idx;
    }
}

// ---------------------------------------------------------------------------
// cleanup: per flagged item, exact-f64 finish using precomputed projections.
__global__ __launch_bounds__(256) void cleanup_kernel(
    const float* __restrict__ q, const float* __restrict__ k,
    const double* __restrict__ hq_d, const double* __restrict__ hk_d,
    const float* __restrict__ b1,
    const float* __restrict__ gam, const float* __restrict__ bet,
    const float* __restrict__ W2, const float* __restrict__ b2,
    const float* __restrict__ gu, float* __restrict__ out,
    const int* __restrict__ cnt, const int* __restrict__ list)
{
    __shared__ double s0[256], s1[256], s2[256], s3[256];
    int tid = threadIdx.x;
    int n = *cnt;
    if (n > LIST_CAP) n = LIST_CAP;
    if (n == 0) return;

    double gw  = (double)gam[tid] * (double)W2[tid];
    double b1d = (double)b1[tid];
    s0[tid] = (double)bet[tid] * (double)W2[tid];
    s1[tid] = gw;
    __syncthreads();
    for (int o = 128; o > 0; o >>= 1) {
        if (tid < o) { s0[tid] += s0[tid + o]; s1[tid] += s1[tid + o]; }
        __syncthreads();
    }
    double bconst = s0[0] + (double)b2[0];
    double gwsum  = s1[0];
    __syncthreads();

    for (int it = blockIdx.x; it < n; it += gridDim.x) {
        int idx = list[it];
        int b   = idx / (Lq * Sk);
        int rem = idx % (Lq * Sk);
        int l = rem / Sk, s = rem % Sk;
        double x = (hq_d[(b * Lq + l) * Hh + tid]
                  + hk_d[(b * Sk + s) * Hh + tid]) + b1d;
        double y = 0.5 * x * (1.0 + erf(x * 0.70710678118654752440));
        const float* qrow = q + (b * Lq + l) * Dd;
        const float* krow = k + (b * Sk + s) * Dd;
        double sp = (double)qrow[tid] * (double)krow[tid]
                  + (double)qrow[tid + 256] * (double)krow[tid + 256];
        s0[tid] = y; s1[tid] = y * y; s2[tid] = y * gw; s3[tid] = sp;
        __syncthreads();
        for (int o = 128; o > 0; o >>= 1) {
            if (tid < o) {
                s0[tid] += s0[tid + o]; s1[tid] += s1[tid + o];
                s2[tid] += s2[tid + o]; s3[tid] += s3[tid + o];
            }
            __syncthreads();
        }
        if (tid == 0) {
            double mu   = s0[0] * (1.0 / 256.0);
            double var  = s1[0] * (1.0 / 256.0) - mu * mu;
            double rstd = 1.0 / sqrt(var + 1e-5);
            double thr  = rstd * (s2[0] - mu * gwsum) + bconst;
            double simv = s3[0] / 22.627416997969522;   // sqrt(512)
            float2 uv = reinterpret_cast<const float2*>(gu)[idx];
            double u0 = fmin(fmax((double)uv.x, 1e-6), 1.0 - 1e-6);
            double u1 = fmin(fmax((double)uv.y, 1e-6), 1.0 - 1e-6);
            double g0 = -log(-log(u0));
            double g1 = -log(-log(u1));
            double t  = 0.2 * (simv - thr) + (g1 - g0);
            out[idx] = t > 0.0 ? 1.0f : 0.0f;
        }
        __syncthreads();
    }
}

// ---------------------------------------------------------------------------
extern "C" void kernel_launch(void* const* d_in, const int* in_sizes, int n_in,
                              void* d_out, int out_size, void* d_ws, size_t ws_size,
                              hipStream_t stream)
{
    const float* q   = (const float*)d_in[0];
    const float* k   = (const float*)d_in[1];
    const float* qg  = (const float*)d_in[2];
    const float* kg  = (const float*)d_in[3];
    const float* W1  = (const float*)d_in[4];
    const float* b1  = (const float*)d_in[5];
    const float* gam = (const float*)d_in[6];
    const float* bet = (const float*)d_in[7];
    const float* W2  = (const float*)d_in[8];
    const float* b2  = (const float*)d_in[9];
    const float* gu  = (const float*)d_in[10];
    float* out = (float*)d_out;

    char*   ws   = (char*)d_ws;
    double* hq_d = (double*)(ws + HQD_OFF);
    double* hk_d = (double*)(ws + HKD_OFF);
    double* part = (double*)(ws + PART_OFF);
    double* gq_d = (double*)(ws + GQD_OFF);
    double* gk_d = (double*)(ws + GKD_OFF);
    float*  hq   = (float*)(ws + HQ_OFF);
    float*  hk   = (float*)(ws + HK_OFF);
    float*  simP = (float*)(ws + SIM_OFF);
    float*  scal = (float*)(ws + SCAL_OFF);
    int*    cnt  = (int*)(ws + CNT_OFF);
    int*    list = (int*)(ws + LIST_OFF);

    proj_fused_kernel<<<17 + NROWS, 256, 0, stream>>>(
        q, k, qg, kg, W1, gam, bet, W2, b2, gq_d, gk_d, scal, cnt, part);
    finalize_kernel<<<NROWS / 2, 256, 0, stream>>>(
        part, gq_d, gk_d, b1, hq_d, hk_d, hq, hk);
    sim_kernel<<<576, 256, 0, stream>>>(q, k, simP);
    main_kernel<<<Bb * 12 * 24, 512, 0, stream>>>(
        hq, hk, simP, gam, W2, scal, gu, out, cnt, list);
    cleanup_kernel<<<768, 256, 0, stream>>>(
        q, k, hq_d, hk_d, b1, gam, bet, W2, b2, gu, out, cnt, list);
}